// Round 13
// baseline (179.786 us; speedup 1.0000x reference)
//
#include <hip/hip_runtime.h>
#include <hip/hip_bf16.h>

typedef unsigned short ushort_t;
typedef __attribute__((ext_vector_type(8))) short short8;
typedef __attribute__((ext_vector_type(4))) float floatx4;

#define TWO_PI 6.28318530717958647692f

__device__ __forceinline__ float bf2f(ushort_t u) {
  union { unsigned u; float f; } v; v.u = ((unsigned)u) << 16; return v.f;
}
__device__ __forceinline__ ushort_t f2bf(float f) {
  union { float f; unsigned u; } v; v.f = f;
  unsigned r = v.u + 0x7FFFu + ((v.u >> 16) & 1u);
  return (ushort_t)(r >> 16);
}
// packed f32x2 -> bf16x2 via HW v_cvt_pk_bf16_f32 (RNE, same as manual path)
__device__ __forceinline__ unsigned pk(float a, float b) {
  union { __hip_bfloat162 h2; unsigned u; } v;
  v.h2 = __float22bfloat162_rn(make_float2(a, b));
  return v.u;
}
__device__ __forceinline__ float ldin(const void* p, int idx, bool bf) {
  return bf ? bf2f(((const ushort_t*)p)[idx]) : ((const float*)p)[idx];
}
__device__ __forceinline__ bool detect_bf16(const void* xv) {
  const ushort_t* us = (const ushort_t*)xv;
  unsigned u = us[threadIdx.x & 63];
  int e = (u >> 7) & 0xFF;
  bool good = (e >= 110) && (e <= 133);
  unsigned long long m = __ballot(good);
  return __builtin_popcountll(m) >= 52;
}
__device__ __forceinline__ uint4 pack8f(const float* p) {
  float4 a = *(const float4*)p, b = *(const float4*)(p + 4);
  uint4 r;
  r.x = pk(a.x, a.y); r.y = pk(a.z, a.w);
  r.z = pk(b.x, b.y); r.w = pk(b.z, b.w);
  return r;
}

// ---------------------------------------------------------------------------
// Prep (fused): blocks 0..255 = featT, blocks 256..511 = wconv with the
// channel shuffle baked in: Wc[n][c*32+j] = conv_w[n][shuf(c)*32+j].
// ---------------------------------------------------------------------------
__global__ __launch_bounds__(256) void paiconv_prep(
    const void* __restrict__ xprobe, const void* __restrict__ feat,
    ushort_t* __restrict__ Ft, const void* __restrict__ W,
    ushort_t* __restrict__ Wc)
{
  const bool bfm = detect_bf16(xprobe);
  const int t = threadIdx.x;
  __shared__ ushort_t tile[64 * 72];

  if (blockIdx.x >= 256) {
    int i = ((blockIdx.x - 256) * 256 + t) << 3;
    int n = i >> 12, rem = i & 4095;
    int c = rem >> 5, j = rem & 31;
    int src = (n << 12) + (((c & 31) * 4 + (c >> 5)) << 5) + j;
    if (bfm) *(uint4*)(Wc + i) = *(const uint4*)((const ushort_t*)W + src);
    else     *(uint4*)(Wc + i) = pack8f((const float*)W + src);
    return;
  }

  const int bb = blockIdx.x >> 5;
  const int n0 = (blockIdx.x & 31) << 6;
  {
    const int c = t & 63, ng = t >> 6;
    size_t base = (((size_t)(bb * 64 + c)) << 11) + n0 + (ng << 4);
    ushort_t v[16];
    if (bfm) {
      const ushort_t* fp_ = (const ushort_t*)feat + base;
      uint4 a = *(const uint4*)fp_, b2 = *(const uint4*)(fp_ + 8);
      unsigned uu[8] = {a.x, a.y, a.z, a.w, b2.x, b2.y, b2.z, b2.w};
#pragma unroll
      for (int e = 0; e < 8; ++e) {
        v[2 * e] = (ushort_t)(uu[e] & 0xffff);
        v[2 * e + 1] = (ushort_t)(uu[e] >> 16);
      }
    } else {
      const float* fp_ = (const float*)feat + base;
#pragma unroll
      for (int k = 0; k < 16; k += 2) {
        unsigned u = pk(fp_[k], fp_[k + 1]);
        v[k] = (ushort_t)(u & 0xffff);
        v[k + 1] = (ushort_t)(u >> 16);
      }
    }
#pragma unroll
    for (int k = 0; k < 16; ++k) tile[(ng * 16 + k) * 72 + c] = v[k];
  }
  __syncthreads();
  {
    const int nn = t >> 2, qtr = t & 3;
    uint4 w0 = *(const uint4*)(tile + nn * 72 + qtr * 16);
    uint4 w1 = *(const uint4*)(tile + nn * 72 + qtr * 16 + 8);
    ushort_t* dst = Ft + (((size_t)(bb * 2048 + n0 + nn)) << 6) + (qtr << 4);
    *(uint4*)dst = w0;
    *(uint4*)(dst + 8) = w1;
  }
}

// ---------------------------------------------------------------------------
// Phase 1: 2 points/block, 3 barriers, ~37.7 KB LDS -> 4 blocks/CU.
// (structure unchanged from round 12; pk now uses HW packed cvt)
// ---------------------------------------------------------------------------
#define SFPT 5184
__global__ __launch_bounds__(256) void paiconv_phase1(
    const void* __restrict__ x,       // [8,3,2048]
    const ushort_t* __restrict__ Ft,  // [16384][64] bf16
    const int*  __restrict__ nbr,     // [8,2048,32]
    const void* __restrict__ Brff,    // [7,32]
    const void* __restrict__ kern,    // [3,32]
    const void* __restrict__ mlpw,    // [64,64]
    const void* __restrict__ mlpb,    // [64]
    ushort_t*   __restrict__ Ag)      // [16384,4096] bf16
{
  const bool bfm = detect_bf16(x);
  const int t = threadIdx.x;
  const int p0 = blockIdx.x << 1;
  const int b  = p0 >> 11;
  const int w = t >> 6, lane = t & 63, lrow = lane & 15, quad = lane >> 4;

  __shared__ ushort_t sRt[64 * 72];
  __shared__ ushort_t sF[2 * SFPT];
  __shared__ ushort_t sP[2 * 32 * 40];
  __shared__ float sRel[2][32][3];
  __shared__ float sDis[2][32];
  __shared__ float sRep[2][3];
  __shared__ float sBr[224];
  __shared__ float sKn[96];
  __shared__ float sMb[64];

  const int gpt = t >> 7, gj = (t >> 2) & 31, gch = t & 3;
  const int gidx = nbr[((p0 + gpt) << 5) + gj];
  const ushort_t* gfr = Ft + (((size_t)(b * 2048 + gidx)) << 6) + (gch << 4);
  uint4 g0 = ((const uint4*)gfr)[0];
  uint4 g1 = ((const uint4*)gfr)[1];

  const int mc = (w << 4) + lrow;
  short8 mb0, mb1;
  if (bfm) {
    const ushort_t* mp = (const ushort_t*)mlpw + mc * 64;
    mb0 = *(const short8*)(mp + (quad << 3));
    mb1 = *(const short8*)(mp + 32 + (quad << 3));
  } else {
    const float* mp = (const float*)mlpw + mc * 64;
    uint4 u0 = pack8f(mp + (quad << 3));
    uint4 u1 = pack8f(mp + 32 + (quad << 3));
    mb0 = *(short8*)&u0;
    mb1 = *(short8*)&u1;
  }

  if (t < 224) sBr[t] = ldin(Brff, t, bfm);
  if (t < 96)  sKn[t] = ldin(kern, t, bfm);
  if (t < 64)  sMb[t] = ldin(mlpb, t, bfm);
  if (t < 64) {
    int pt = t >> 5, i = t & 31;
    int p = p0 + pt;
    int idx  = nbr[(p << 5) + i];
    int idx0 = nbr[(p << 5)];
    int xo = b * 6144;
    float rx = ldin(x, xo + idx0, bfm);
    float ry = ldin(x, xo + 2048 + idx0, bfm);
    float rz = ldin(x, xo + 4096 + idx0, bfm);
    float cx = ldin(x, xo + idx, bfm);
    float cy = ldin(x, xo + 2048 + idx, bfm);
    float cz = ldin(x, xo + 4096 + idx, bfm);
    float dx = cx - rx, dy = cy - ry, dz = cz - rz;
    sRel[pt][i][0] = dx; sRel[pt][i][1] = dy; sRel[pt][i][2] = dz;
    sDis[pt][i] = sqrtf(dx * dx + dy * dy + dz * dz);
    if (i == 0) { sRep[pt][0] = rx; sRep[pt][1] = ry; sRep[pt][2] = rz; }
  }
  __syncthreads();   // b1

  // ---- R^T build (all 256 threads) ----
  {
    int jn = t >> 2, mh = (t & 3) << 3;
    int pt = jn >> 5, j = jn & 31;
    float pos[7];
    pos[0] = TWO_PI * sRep[pt][0]; pos[1] = TWO_PI * sRep[pt][1];
    pos[2] = TWO_PI * sRep[pt][2];
    pos[3] = TWO_PI * sRel[pt][j][0]; pos[4] = TWO_PI * sRel[pt][j][1];
    pos[5] = TWO_PI * sRel[pt][j][2];
    pos[6] = TWO_PI * sDis[pt][j];
    unsigned sw[4], cw[4];
#pragma unroll
    for (int mm = 0; mm < 8; mm += 2) {
      float a0 = 0.f, a1 = 0.f;
#pragma unroll
      for (int d = 0; d < 7; ++d) {
        a0 += pos[d] * sBr[d * 32 + mh + mm];
        a1 += pos[d] * sBr[d * 32 + mh + mm + 1];
      }
      sw[mm >> 1] = pk(__sinf(a0), __sinf(a1));
      cw[mm >> 1] = pk(__cosf(a0), __cosf(a1));
    }
    ushort_t* rb = sRt + jn * 72;
    *(uint4*)(rb + mh)      = make_uint4(sw[0], sw[1], sw[2], sw[3]);
    *(uint4*)(rb + 32 + mh) = make_uint4(cw[0], cw[1], cw[2], cw[3]);
  }

  // ---- perm build on 128 threads: t = pt*64 + h*32 + j, partner = t^32 ----
  if (t < 128) {
    int pt = t >> 6, j = t & 31, h = (t >> 5) & 1;
    float k0 = sKn[j], k1 = sKn[32 + j], k2 = sKn[64 + j];
    float col[16];
    float s1 = 0.f;
#pragma unroll
    for (int il = 0; il < 16; ++il) {
      int i = h * 16 + il;
      float v = sRel[pt][i][0] * k0 + sRel[pt][i][1] * k1 + sRel[pt][i][2] * k2;
      if (i == 0 && j == 0) v += 1.0f;
      v = fmaxf(v, 0.f);
      col[il] = v; s1 += v;
    }
    s1 += __shfl_xor(s1, 32, 64);
    float inv1 = 1.0f / (s1 + 1e-6f);
    float s2 = 0.f;
#pragma unroll
    for (int il = 0; il < 16; ++il) { float v = col[il] * inv1; v = v * v; col[il] = v; s2 += v; }
    s2 += __shfl_xor(s2, 32, 64);
    float inv2 = 1.0f / (s2 + 1e-6f);
    unsigned pw[8];
#pragma unroll
    for (int il = 0; il < 16; il += 2) {
      float v0 = col[il] * inv2;     v0 = (v0 > 0.1f) ? v0 : 0.f;
      float v1 = col[il + 1] * inv2; v1 = (v1 > 0.1f) ? v1 : 0.f;
      pw[il >> 1] = pk(v0, v1);
    }
    ushort_t* dst = sP + pt * 1280 + j * 40 + h * 16;
    *(uint4*)dst       = make_uint4(pw[0], pw[1], pw[2], pw[3]);
    *(uint4*)(dst + 8) = make_uint4(pw[4], pw[5], pw[6], pw[7]);
  }
  __syncthreads();   // b2

  // ---- mlp MFMA -> sF rows 64+mc ----
  {
    int row = 64 + mc;
    int rbase = row * 40 + ((4 + w) << 3);
    float bv = sMb[mc];
#pragma unroll
    for (int mt = 0; mt < 4; ++mt) {
      const ushort_t* rp = sRt + (mt * 16 + lrow) * 72 + (quad << 3);
      short8 a0 = *(const short8*)rp;
      short8 a1 = *(const short8*)(rp + 32);
      floatx4 acc = {0.f, 0.f, 0.f, 0.f};
      acc = __builtin_amdgcn_mfma_f32_16x16x32_bf16(a0, mb0, acc, 0, 0, 0);
      acc = __builtin_amdgcn_mfma_f32_16x16x32_bf16(a1, mb1, acc, 0, 0, 0);
      int pt = mt >> 1;
      int j0 = ((mt & 1) << 4) + (quad << 2);
      *(uint2*)(sF + pt * SFPT + rbase + j0) =
          make_uint2(pk(acc[0] + bv, acc[1] + bv), pk(acc[2] + bv, acc[3] + bv));
    }
  }
  // ---- gather regs -> sF rows gch*16+e ----
  {
    ushort_t* fp_ = sF + gpt * SFPT + gch * 648 + gj;
    unsigned uu[8] = {g0.x, g0.y, g0.z, g0.w, g1.x, g1.y, g1.z, g1.w};
#pragma unroll
    for (int u = 0; u < 8; ++u) {
      fp_[(2 * u) * 40]     = (ushort_t)(uu[u] & 0xffff);
      fp_[(2 * u + 1) * 40] = (ushort_t)(uu[u] >> 16);
    }
  }
  __syncthreads();   // b3

  // ---- F@P via MFMA -> global A ----
  {
#pragma unroll
    for (int pt = 0; pt < 2; ++pt) {
      const ushort_t* Pp = sP + pt * 1280;
      short8 a0 = *(const short8*)(Pp + lrow * 40 + (quad << 3));
      short8 a1 = *(const short8*)(Pp + (16 + lrow) * 40 + (quad << 3));
      size_t prow = ((size_t)(p0 + pt)) << 12;
#pragma unroll
      for (int nt = 0; nt < 2; ++nt) {
        int blk = w * 2 + nt;
        int cidx = (blk << 4) + lrow;
        short8 bfg = *(const short8*)(sF + pt * SFPT + cidx * 40 + (blk << 3) + (quad << 3));
        floatx4 z = {0.f, 0.f, 0.f, 0.f};
        floatx4 c0 = __builtin_amdgcn_mfma_f32_16x16x32_bf16(a0, bfg, z, 0, 0, 0);
        floatx4 c1 = __builtin_amdgcn_mfma_f32_16x16x32_bf16(a1, bfg, z, 0, 0, 0);
        ushort_t* ad = Ag + prow + cidx * 32 + (quad << 2);
        *(uint2*)ad        = make_uint2(pk(c0[0], c0[1]), pk(c0[2], c0[3]));
        *(uint2*)(ad + 16) = make_uint2(pk(c1[0], c1[1]), pk(c1[2], c1[3]));
      }
    }
  }
}

// ---------------------------------------------------------------------------
// Phase 2: bf16 MFMA GEMM, BM=64 BN=128 BK=64, split-K=2, grid (256,2).
// Dbuf LDS, one barrier per half-iter, manually-unrolled depth-2 prefetch.
// (unchanged from round 12 — best so far)
// ---------------------------------------------------------------------------
__global__ __launch_bounds__(256) void paiconv_gemm(
    const ushort_t* __restrict__ A,    // [16384,4096] bf16
    const ushort_t* __restrict__ Wc,   // [128,4096] bf16 (shuffle-permuted)
    float* __restrict__ part)          // [2][16384][128] fp32
{
  __shared__ ushort_t lA[2][64 * 72];
  __shared__ ushort_t lB[2][128 * 72];
  const int m0 = blockIdx.x << 6;
  const int K0 = blockIdx.y << 11;
  const int t = threadIdx.x;
  const int w = t >> 6, lane = t & 63;
  const int wm = w & 1, wn = w >> 1, lrow = lane & 15, quad = lane >> 4;

  const int ar = t >> 2, ac = (t & 3) << 4;
  const int wr = t >> 1, wc = (t & 1) << 5;
  const ushort_t* Ap = A + (size_t)(m0 + ar) * 4096 + K0 + ac;
  const ushort_t* Wp = Wc + (size_t)wr * 4096 + K0 + wc;

  uint4 ea0 = *(const uint4*)Ap,        ea1 = *(const uint4*)(Ap + 8);
  uint4 eb0 = *(const uint4*)Wp,        eb1 = *(const uint4*)(Wp + 8);
  uint4 eb2 = *(const uint4*)(Wp + 16), eb3 = *(const uint4*)(Wp + 24);
  uint4 oa0 = *(const uint4*)(Ap + 64),      oa1 = *(const uint4*)(Ap + 72);
  uint4 ob0 = *(const uint4*)(Wp + 64),      ob1 = *(const uint4*)(Wp + 72);
  uint4 ob2 = *(const uint4*)(Wp + 80),      ob3 = *(const uint4*)(Wp + 88);

  floatx4 acc[2][4];
#pragma unroll
  for (int i = 0; i < 2; ++i)
#pragma unroll
    for (int j = 0; j < 4; ++j) acc[i][j] = (floatx4){0.f, 0.f, 0.f, 0.f};

  for (int kb = 0; kb < 32; kb += 2) {
    {
      ushort_t* la = lA[0];
      ushort_t* lb = lB[0];
      *(uint4*)(la + ar * 72 + ac)      = ea0;
      *(uint4*)(la + ar * 72 + ac + 8)  = ea1;
      *(uint4*)(lb + wr * 72 + wc)      = eb0;
      *(uint4*)(lb + wr * 72 + wc + 8)  = eb1;
      *(uint4*)(lb + wr * 72 + wc + 16) = eb2;
      *(uint4*)(lb + wr * 72 + wc + 24) = eb3;
      __syncthreads();
      if (kb + 2 < 32) {
        int off = (kb + 2) << 6;
        ea0 = *(const uint4*)(Ap + off);      ea1 = *(const uint4*)(Ap + off + 8);
        eb0 = *(const uint4*)(Wp + off);      eb1 = *(const uint4*)(Wp + off + 8);
        eb2 = *(const uint4*)(Wp + off + 16); eb3 = *(const uint4*)(Wp + off + 24);
      }
#pragma unroll
      for (int kk = 0; kk < 2; ++kk) {
        short8 af0 = *(const short8*)(la + ((wm << 5) + lrow) * 72 + (kk << 5) + (quad << 3));
        short8 af1 = *(const short8*)(la + ((wm << 5) + 16 + lrow) * 72 + (kk << 5) + (quad << 3));
#pragma unroll
        for (int ni = 0; ni < 4; ++ni) {
          short8 bf = *(const short8*)(lb + ((wn << 6) + (ni << 4) + lrow) * 72 +
                                       (kk << 5) + (quad << 3));
          acc[0][ni] = __builtin_amdgcn_mfma_f32_16x16x32_bf16(af0, bf, acc[0][ni], 0, 0, 0);
          acc[1][ni] = __builtin_amdgcn_mfma_f32_16x16x32_bf16(af1, bf, acc[1][ni], 0, 0, 0);
        }
      }
    }
    {
      ushort_t* la = lA[1];
      ushort_t* lb = lB[1];
      *(uint4*)(la + ar * 72 + ac)      = oa0;
      *(uint4*)(la + ar * 72 + ac + 8)  = oa1;
      *(uint4*)(lb + wr * 72 + wc)      = ob0;
      *(uint4*)(lb + wr * 72 + wc + 8)  = ob1;
      *(uint4*)(lb + wr * 72 + wc + 16) = ob2;
      *(uint4*)(lb + wr * 72 + wc + 24) = ob3;
      __syncthreads();
      if (kb + 3 < 32) {
        int off = (kb + 3) << 6;
        oa0 = *(const uint4*)(Ap + off);      oa1 = *(const uint4*)(Ap + off + 8);
        ob0 = *(const uint4*)(Wp + off);      ob1 = *(const uint4*)(Wp + off + 8);
        ob2 = *(const uint4*)(Wp + off + 16); ob3 = *(const uint4*)(Wp + off + 24);
      }
#pragma unroll
      for (int kk = 0; kk < 2; ++kk) {
        short8 af0 = *(const short8*)(la + ((wm << 5) + lrow) * 72 + (kk << 5) + (quad << 3));
        short8 af1 = *(const short8*)(la + ((wm << 5) + 16 + lrow) * 72 + (kk << 5) + (quad << 3));
#pragma unroll
        for (int ni = 0; ni < 4; ++ni) {
          short8 bf = *(const short8*)(lb + ((wn << 6) + (ni << 4) + lrow) * 72 +
                                       (kk << 5) + (quad << 3));
          acc[0][ni] = __builtin_amdgcn_mfma_f32_16x16x32_bf16(af0, bf, acc[0][ni], 0, 0, 0);
          acc[1][ni] = __builtin_amdgcn_mfma_f32_16x16x32_bf16(af1, bf, acc[1][ni], 0, 0, 0);
        }
      }
    }
  }

  float* dst = part + ((size_t)blockIdx.y << 21);
#pragma unroll
  for (int mi = 0; mi < 2; ++mi)
#pragma unroll
    for (int ni = 0; ni < 4; ++ni)
#pragma unroll
      for (int r = 0; r < 4; ++r) {
        int m = m0 + (wm << 5) + (mi << 4) + (quad << 2) + r;
        int n = (wn << 6) + (ni << 4) + lrow;
        dst[(size_t)m * 128 + n] = acc[mi][ni][r];
      }
}

// ---------------------------------------------------------------------------
// Reduce: sum 2 split-K partials + bias (float4 loads), transpose to out.
// ---------------------------------------------------------------------------
__global__ __launch_bounds__(256) void paiconv_reduce(
    const void* __restrict__ xprobe, const float* __restrict__ part,
    const void* __restrict__ bias, void* __restrict__ out)
{
  const bool bfm = detect_bf16(xprobe);
  __shared__ float buf[128 * 65];
  const int m0 = blockIdx.x << 6;
  const int b = m0 >> 11, n0 = m0 & 2047;
  const int t = threadIdx.x;

#pragma unroll
  for (int i = 0; i < 8; ++i) {
    int idx = (i * 256 + t) << 2;
    int mt = idx >> 7, c = idx & 127;
    size_t o = (size_t)(m0 + mt) * 128 + c;
    float4 v0 = *(const float4*)(part + o);
    float4 v1 = *(const float4*)(part + (1u << 21) + o);
    buf[(c + 0) * 65 + mt] = v0.x + v1.x + ldin(bias, c + 0, bfm);
    buf[(c + 1) * 65 + mt] = v0.y + v1.y + ldin(bias, c + 1, bfm);
    buf[(c + 2) * 65 + mt] = v0.z + v1.z + ldin(bias, c + 2, bfm);
    buf[(c + 3) * 65 + mt] = v0.w + v1.w + ldin(bias, c + 3, bfm);
  }
  __syncthreads();
#pragma unroll
  for (int i = 0; i < 8; ++i) {
    int idx = (i * 256 + t) << 2;
    int c = idx >> 6, nl = idx & 63;
    float v0 = buf[c * 65 + nl], v1 = buf[c * 65 + nl + 1];
    float v2 = buf[c * 65 + nl + 2], v3 = buf[c * 65 + nl + 3];
    size_t o = (size_t)b * 262144 + (size_t)c * 2048 + n0 + nl;
    if (bfm) *(uint2*)((ushort_t*)out + o) = make_uint2(pk(v0, v1), pk(v2, v3));
    else     *(float4*)((float*)out + o) = make_float4(v0, v1, v2, v3);
  }
}

extern "C" void kernel_launch(void* const* d_in, const int* in_sizes, int n_in,
                              void* d_out, int out_size, void* d_ws, size_t ws_size,
                              hipStream_t stream) {
  const void* x     = d_in[0];
  const void* feat  = d_in[1];
  const int*  nbr   = (const int*)d_in[2];
  const void* Brff  = d_in[3];
  const void* kern  = d_in[4];
  const void* mlpw  = d_in[5];
  const void* mlpb  = d_in[6];
  const void* convw = d_in[7];
  const void* convb = d_in[8];

  char* ws = (char*)d_ws;
  ushort_t* A   = (ushort_t*)ws;                          // 128 MiB
  ushort_t* Wcv = (ushort_t*)(ws + (size_t)134217728);    // 1 MiB
  float*    prt = (float*)(ws + (size_t)135266304);       // 16 MiB
  ushort_t* Ft  = (ushort_t*)(ws + (size_t)152043520);    // 2 MiB

  paiconv_prep<<<512, 256, 0, stream>>>(x, feat, Ft, convw, Wcv);
  paiconv_phase1<<<8192, 256, 0, stream>>>(x, Ft, nbr, Brff, kern, mlpw, mlpb, A);
  paiconv_gemm<<<dim3(256, 2, 1), 256, 0, stream>>>(A, Wcv, prt);
  paiconv_reduce<<<256, 256, 0, stream>>>(x, prt, convb, d_out);
}

// Round 14
// 167.879 us; speedup vs baseline: 1.0709x; 1.0709x over previous
//
#include <hip/hip_runtime.h>
#include <hip/hip_bf16.h>

typedef unsigned short ushort_t;
typedef __attribute__((ext_vector_type(8))) short short8;
typedef __attribute__((ext_vector_type(4))) float floatx4;

#define TWO_PI 6.28318530717958647692f

__device__ __forceinline__ float bf2f(ushort_t u) {
  union { unsigned u; float f; } v; v.u = ((unsigned)u) << 16; return v.f;
}
__device__ __forceinline__ unsigned pk(float a, float b) {
  union { __hip_bfloat162 h2; unsigned u; } v;
  v.h2 = __float22bfloat162_rn(make_float2(a, b));
  return v.u;
}
__device__ __forceinline__ float ldin(const void* p, int idx, bool bf) {
  return bf ? bf2f(((const ushort_t*)p)[idx]) : ((const float*)p)[idx];
}
__device__ __forceinline__ bool detect_bf16(const void* xv) {
  const ushort_t* us = (const ushort_t*)xv;
  unsigned u = us[threadIdx.x & 63];
  int e = (u >> 7) & 0xFF;
  bool good = (e >= 110) && (e <= 133);
  unsigned long long m = __ballot(good);
  return __builtin_popcountll(m) >= 52;
}
__device__ __forceinline__ uint4 pack8f(const float* p) {
  float4 a = *(const float4*)p, b = *(const float4*)(p + 4);
  uint4 r;
  r.x = pk(a.x, a.y); r.y = pk(a.z, a.w);
  r.z = pk(b.x, b.y); r.w = pk(b.z, b.w);
  return r;
}

// ---------------------------------------------------------------------------
// Prep (fused): blocks 0..255 = featT, blocks 256..511 = wconv (shuffle baked).
// ---------------------------------------------------------------------------
__global__ __launch_bounds__(256) void paiconv_prep(
    const void* __restrict__ xprobe, const void* __restrict__ feat,
    ushort_t* __restrict__ Ft, const void* __restrict__ W,
    ushort_t* __restrict__ Wc)
{
  const bool bfm = detect_bf16(xprobe);
  const int t = threadIdx.x;
  __shared__ ushort_t tile[64 * 72];

  if (blockIdx.x >= 256) {
    int i = ((blockIdx.x - 256) * 256 + t) << 3;
    int n = i >> 12, rem = i & 4095;
    int c = rem >> 5, j = rem & 31;
    int src = (n << 12) + (((c & 31) * 4 + (c >> 5)) << 5) + j;
    if (bfm) *(uint4*)(Wc + i) = *(const uint4*)((const ushort_t*)W + src);
    else     *(uint4*)(Wc + i) = pack8f((const float*)W + src);
    return;
  }

  const int bb = blockIdx.x >> 5;
  const int n0 = (blockIdx.x & 31) << 6;
  {
    const int c = t & 63, ng = t >> 6;
    size_t base = (((size_t)(bb * 64 + c)) << 11) + n0 + (ng << 4);
    ushort_t v[16];
    if (bfm) {
      const ushort_t* fp_ = (const ushort_t*)feat + base;
      uint4 a = *(const uint4*)fp_, b2 = *(const uint4*)(fp_ + 8);
      unsigned uu[8] = {a.x, a.y, a.z, a.w, b2.x, b2.y, b2.z, b2.w};
#pragma unroll
      for (int e = 0; e < 8; ++e) {
        v[2 * e] = (ushort_t)(uu[e] & 0xffff);
        v[2 * e + 1] = (ushort_t)(uu[e] >> 16);
      }
    } else {
      const float* fp_ = (const float*)feat + base;
#pragma unroll
      for (int k = 0; k < 16; k += 2) {
        unsigned u = pk(fp_[k], fp_[k + 1]);
        v[k] = (ushort_t)(u & 0xffff);
        v[k + 1] = (ushort_t)(u >> 16);
      }
    }
#pragma unroll
    for (int k = 0; k < 16; ++k) tile[(ng * 16 + k) * 72 + c] = v[k];
  }
  __syncthreads();
  {
    const int nn = t >> 2, qtr = t & 3;
    uint4 w0 = *(const uint4*)(tile + nn * 72 + qtr * 16);
    uint4 w1 = *(const uint4*)(tile + nn * 72 + qtr * 16 + 8);
    ushort_t* dst = Ft + (((size_t)(bb * 2048 + n0 + nn)) << 6) + (qtr << 4);
    *(uint4*)dst = w0;
    *(uint4*)(dst + 8) = w1;
  }
}

// ---------------------------------------------------------------------------
// Phase 1: 2 points/block, POINT-SEQUENTIAL sF (single 10.4 KB buffer),
// 5 barriers, ~27.3 KB LDS -> 5 blocks/CU (occupancy ~48%).
// ---------------------------------------------------------------------------
#define SFPT 5184
__global__ __launch_bounds__(256) void paiconv_phase1(
    const void* __restrict__ x,       // [8,3,2048]
    const ushort_t* __restrict__ Ft,  // [16384][64] bf16
    const int*  __restrict__ nbr,     // [8,2048,32]
    const void* __restrict__ Brff,    // [7,32]
    const void* __restrict__ kern,    // [3,32]
    const void* __restrict__ mlpw,    // [64,64]
    const void* __restrict__ mlpb,    // [64]
    ushort_t*   __restrict__ Ag)      // [16384,4096] bf16
{
  const bool bfm = detect_bf16(x);
  const int t = threadIdx.x;
  const int p0 = blockIdx.x << 1;
  const int b  = p0 >> 11;
  const int w = t >> 6, lane = t & 63, lrow = lane & 15, quad = lane >> 4;

  __shared__ ushort_t sRt[64 * 72];     // 9.2 KB (both points)
  __shared__ ushort_t sF[SFPT];         // 10.4 KB (ONE point at a time)
  __shared__ ushort_t sP[2 * 32 * 40];  // 5.1 KB (both points)
  __shared__ float sRel[2][32][3];
  __shared__ float sDis[2][32];
  __shared__ float sRep[2][3];
  __shared__ float sBr[224];
  __shared__ float sKn[96];
  __shared__ float sMb[64];

  // gather prefetch: 16 channels (2 uint4)/thread; gpt = which point
  const int gpt = t >> 7, gj = (t >> 2) & 31, gch = t & 3;
  const int gidx = nbr[((p0 + gpt) << 5) + gj];
  const ushort_t* gfr = Ft + (((size_t)(b * 2048 + gidx)) << 6) + (gch << 4);
  uint4 g0 = ((const uint4*)gfr)[0];
  uint4 g1 = ((const uint4*)gfr)[1];

  const int mc = (w << 4) + lrow;
  short8 mb0, mb1;
  if (bfm) {
    const ushort_t* mp = (const ushort_t*)mlpw + mc * 64;
    mb0 = *(const short8*)(mp + (quad << 3));
    mb1 = *(const short8*)(mp + 32 + (quad << 3));
  } else {
    const float* mp = (const float*)mlpw + mc * 64;
    uint4 u0 = pack8f(mp + (quad << 3));
    uint4 u1 = pack8f(mp + 32 + (quad << 3));
    mb0 = *(short8*)&u0;
    mb1 = *(short8*)&u1;
  }

  if (t < 224) sBr[t] = ldin(Brff, t, bfm);
  if (t < 96)  sKn[t] = ldin(kern, t, bfm);
  if (t < 64)  sMb[t] = ldin(mlpb, t, bfm);
  if (t < 64) {
    int pt = t >> 5, i = t & 31;
    int p = p0 + pt;
    int idx  = nbr[(p << 5) + i];
    int idx0 = nbr[(p << 5)];
    int xo = b * 6144;
    float rx = ldin(x, xo + idx0, bfm);
    float ry = ldin(x, xo + 2048 + idx0, bfm);
    float rz = ldin(x, xo + 4096 + idx0, bfm);
    float cx = ldin(x, xo + idx, bfm);
    float cy = ldin(x, xo + 2048 + idx, bfm);
    float cz = ldin(x, xo + 4096 + idx, bfm);
    float dx = cx - rx, dy = cy - ry, dz = cz - rz;
    sRel[pt][i][0] = dx; sRel[pt][i][1] = dy; sRel[pt][i][2] = dz;
    sDis[pt][i] = sqrtf(dx * dx + dy * dy + dz * dz);
    if (i == 0) { sRep[pt][0] = rx; sRep[pt][1] = ry; sRep[pt][2] = rz; }
  }
  __syncthreads();   // b1

  // ---- I1: R^T build (all 256) + perm build (t<128) ----
  {
    int jn = t >> 2, mh = (t & 3) << 3;
    int pt = jn >> 5, j = jn & 31;
    float pos[7];
    pos[0] = TWO_PI * sRep[pt][0]; pos[1] = TWO_PI * sRep[pt][1];
    pos[2] = TWO_PI * sRep[pt][2];
    pos[3] = TWO_PI * sRel[pt][j][0]; pos[4] = TWO_PI * sRel[pt][j][1];
    pos[5] = TWO_PI * sRel[pt][j][2];
    pos[6] = TWO_PI * sDis[pt][j];
    unsigned sw[4], cw[4];
#pragma unroll
    for (int mm = 0; mm < 8; mm += 2) {
      float a0 = 0.f, a1 = 0.f;
#pragma unroll
      for (int d = 0; d < 7; ++d) {
        a0 += pos[d] * sBr[d * 32 + mh + mm];
        a1 += pos[d] * sBr[d * 32 + mh + mm + 1];
      }
      sw[mm >> 1] = pk(__sinf(a0), __sinf(a1));
      cw[mm >> 1] = pk(__cosf(a0), __cosf(a1));
    }
    ushort_t* rb = sRt + jn * 72;
    *(uint4*)(rb + mh)      = make_uint4(sw[0], sw[1], sw[2], sw[3]);
    *(uint4*)(rb + 32 + mh) = make_uint4(cw[0], cw[1], cw[2], cw[3]);
  }
  if (t < 128) {
    int pt = t >> 6, j = t & 31, h = (t >> 5) & 1;
    float k0 = sKn[j], k1 = sKn[32 + j], k2 = sKn[64 + j];
    float col[16];
    float s1 = 0.f;
#pragma unroll
    for (int il = 0; il < 16; ++il) {
      int i = h * 16 + il;
      float v = sRel[pt][i][0] * k0 + sRel[pt][i][1] * k1 + sRel[pt][i][2] * k2;
      if (i == 0 && j == 0) v += 1.0f;
      v = fmaxf(v, 0.f);
      col[il] = v; s1 += v;
    }
    s1 += __shfl_xor(s1, 32, 64);
    float inv1 = 1.0f / (s1 + 1e-6f);
    float s2 = 0.f;
#pragma unroll
    for (int il = 0; il < 16; ++il) { float v = col[il] * inv1; v = v * v; col[il] = v; s2 += v; }
    s2 += __shfl_xor(s2, 32, 64);
    float inv2 = 1.0f / (s2 + 1e-6f);
    unsigned pw[8];
#pragma unroll
    for (int il = 0; il < 16; il += 2) {
      float v0 = col[il] * inv2;     v0 = (v0 > 0.1f) ? v0 : 0.f;
      float v1 = col[il + 1] * inv2; v1 = (v1 > 0.1f) ? v1 : 0.f;
      pw[il >> 1] = pk(v0, v1);
    }
    ushort_t* dst = sP + pt * 1280 + j * 40 + h * 16;
    *(uint4*)dst       = make_uint4(pw[0], pw[1], pw[2], pw[3]);
    *(uint4*)(dst + 8) = make_uint4(pw[4], pw[5], pw[6], pw[7]);
  }
  __syncthreads();   // b2

  const int rbase = (64 + mc) * 40 + ((4 + w) << 3);
  const float bv = sMb[mc];

#pragma unroll
  for (int pt = 0; pt < 2; ++pt) {
    // ---- fill sF for point pt: mlp MFMA rows 64+c + gather rows 0..63 ----
    {
#pragma unroll
      for (int half = 0; half < 2; ++half) {          // j halves 0-15 / 16-31
        int mt = pt * 2 + half;
        const ushort_t* rp = sRt + (mt * 16 + lrow) * 72 + (quad << 3);
        short8 a0 = *(const short8*)rp;
        short8 a1 = *(const short8*)(rp + 32);
        floatx4 acc = {0.f, 0.f, 0.f, 0.f};
        acc = __builtin_amdgcn_mfma_f32_16x16x32_bf16(a0, mb0, acc, 0, 0, 0);
        acc = __builtin_amdgcn_mfma_f32_16x16x32_bf16(a1, mb1, acc, 0, 0, 0);
        int j0 = (half << 4) + (quad << 2);
        *(uint2*)(sF + rbase + j0) =
            make_uint2(pk(acc[0] + bv, acc[1] + bv), pk(acc[2] + bv, acc[3] + bv));
      }
      if (gpt == pt) {
        ushort_t* fp_ = sF + gch * 648 + gj;
        unsigned uu[8] = {g0.x, g0.y, g0.z, g0.w, g1.x, g1.y, g1.z, g1.w};
#pragma unroll
        for (int u = 0; u < 8; ++u) {
          fp_[(2 * u) * 40]     = (ushort_t)(uu[u] & 0xffff);
          fp_[(2 * u + 1) * 40] = (ushort_t)(uu[u] >> 16);
        }
      }
    }
    __syncthreads();   // b3 / b5

    // ---- F@P via MFMA -> global A for point pt ----
    {
      const ushort_t* Pp = sP + pt * 1280;
      short8 a0 = *(const short8*)(Pp + lrow * 40 + (quad << 3));
      short8 a1 = *(const short8*)(Pp + (16 + lrow) * 40 + (quad << 3));
      size_t prow = ((size_t)(p0 + pt)) << 12;
#pragma unroll
      for (int nt = 0; nt < 2; ++nt) {
        int blk = w * 2 + nt;
        int cidx = (blk << 4) + lrow;
        short8 bfg = *(const short8*)(sF + cidx * 40 + (blk << 3) + (quad << 3));
        floatx4 z = {0.f, 0.f, 0.f, 0.f};
        floatx4 c0 = __builtin_amdgcn_mfma_f32_16x16x32_bf16(a0, bfg, z, 0, 0, 0);
        floatx4 c1 = __builtin_amdgcn_mfma_f32_16x16x32_bf16(a1, bfg, z, 0, 0, 0);
        ushort_t* ad = Ag + prow + cidx * 32 + (quad << 2);
        *(uint2*)ad        = make_uint2(pk(c0[0], c0[1]), pk(c0[2], c0[3]));
        *(uint2*)(ad + 16) = make_uint2(pk(c1[0], c1[1]), pk(c1[2], c1[3]));
      }
    }
    if (pt == 0) __syncthreads();   // b4 (WAR: pt1 fill vs pt0 reads)
  }
}

// ---------------------------------------------------------------------------
// Phase 2: bf16 MFMA GEMM, BM=64 BN=128 BK=64, split-K=2, grid (256,2).
// Dbuf LDS, one barrier per half-iter, manual depth-2 prefetch. (r12 — best)
// ---------------------------------------------------------------------------
__global__ __launch_bounds__(256) void paiconv_gemm(
    const ushort_t* __restrict__ A,
    const ushort_t* __restrict__ Wc,
    float* __restrict__ part)
{
  __shared__ ushort_t lA[2][64 * 72];
  __shared__ ushort_t lB[2][128 * 72];
  const int m0 = blockIdx.x << 6;
  const int K0 = blockIdx.y << 11;
  const int t = threadIdx.x;
  const int w = t >> 6, lane = t & 63;
  const int wm = w & 1, wn = w >> 1, lrow = lane & 15, quad = lane >> 4;

  const int ar = t >> 2, ac = (t & 3) << 4;
  const int wr = t >> 1, wc = (t & 1) << 5;
  const ushort_t* Ap = A + (size_t)(m0 + ar) * 4096 + K0 + ac;
  const ushort_t* Wp = Wc + (size_t)wr * 4096 + K0 + wc;

  uint4 ea0 = *(const uint4*)Ap,        ea1 = *(const uint4*)(Ap + 8);
  uint4 eb0 = *(const uint4*)Wp,        eb1 = *(const uint4*)(Wp + 8);
  uint4 eb2 = *(const uint4*)(Wp + 16), eb3 = *(const uint4*)(Wp + 24);
  uint4 oa0 = *(const uint4*)(Ap + 64),      oa1 = *(const uint4*)(Ap + 72);
  uint4 ob0 = *(const uint4*)(Wp + 64),      ob1 = *(const uint4*)(Wp + 72);
  uint4 ob2 = *(const uint4*)(Wp + 80),      ob3 = *(const uint4*)(Wp + 88);

  floatx4 acc[2][4];
#pragma unroll
  for (int i = 0; i < 2; ++i)
#pragma unroll
    for (int j = 0; j < 4; ++j) acc[i][j] = (floatx4){0.f, 0.f, 0.f, 0.f};

  for (int kb = 0; kb < 32; kb += 2) {
    {
      ushort_t* la = lA[0];
      ushort_t* lb = lB[0];
      *(uint4*)(la + ar * 72 + ac)      = ea0;
      *(uint4*)(la + ar * 72 + ac + 8)  = ea1;
      *(uint4*)(lb + wr * 72 + wc)      = eb0;
      *(uint4*)(lb + wr * 72 + wc + 8)  = eb1;
      *(uint4*)(lb + wr * 72 + wc + 16) = eb2;
      *(uint4*)(lb + wr * 72 + wc + 24) = eb3;
      __syncthreads();
      if (kb + 2 < 32) {
        int off = (kb + 2) << 6;
        ea0 = *(const uint4*)(Ap + off);      ea1 = *(const uint4*)(Ap + off + 8);
        eb0 = *(const uint4*)(Wp + off);      eb1 = *(const uint4*)(Wp + off + 8);
        eb2 = *(const uint4*)(Wp + off + 16); eb3 = *(const uint4*)(Wp + off + 24);
      }
#pragma unroll
      for (int kk = 0; kk < 2; ++kk) {
        short8 af0 = *(const short8*)(la + ((wm << 5) + lrow) * 72 + (kk << 5) + (quad << 3));
        short8 af1 = *(const short8*)(la + ((wm << 5) + 16 + lrow) * 72 + (kk << 5) + (quad << 3));
#pragma unroll
        for (int ni = 0; ni < 4; ++ni) {
          short8 bf = *(const short8*)(lb + ((wn << 6) + (ni << 4) + lrow) * 72 +
                                       (kk << 5) + (quad << 3));
          acc[0][ni] = __builtin_amdgcn_mfma_f32_16x16x32_bf16(af0, bf, acc[0][ni], 0, 0, 0);
          acc[1][ni] = __builtin_amdgcn_mfma_f32_16x16x32_bf16(af1, bf, acc[1][ni], 0, 0, 0);
        }
      }
    }
    {
      ushort_t* la = lA[1];
      ushort_t* lb = lB[1];
      *(uint4*)(la + ar * 72 + ac)      = oa0;
      *(uint4*)(la + ar * 72 + ac + 8)  = oa1;
      *(uint4*)(lb + wr * 72 + wc)      = ob0;
      *(uint4*)(lb + wr * 72 + wc + 8)  = ob1;
      *(uint4*)(lb + wr * 72 + wc + 16) = ob2;
      *(uint4*)(lb + wr * 72 + wc + 24) = ob3;
      __syncthreads();
      if (kb + 3 < 32) {
        int off = (kb + 3) << 6;
        oa0 = *(const uint4*)(Ap + off);      oa1 = *(const uint4*)(Ap + off + 8);
        ob0 = *(const uint4*)(Wp + off);      ob1 = *(const uint4*)(Wp + off + 8);
        ob2 = *(const uint4*)(Wp + off + 16); ob3 = *(const uint4*)(Wp + off + 24);
      }
#pragma unroll
      for (int kk = 0; kk < 2; ++kk) {
        short8 af0 = *(const short8*)(la + ((wm << 5) + lrow) * 72 + (kk << 5) + (quad << 3));
        short8 af1 = *(const short8*)(la + ((wm << 5) + 16 + lrow) * 72 + (kk << 5) + (quad << 3));
#pragma unroll
        for (int ni = 0; ni < 4; ++ni) {
          short8 bf = *(const short8*)(lb + ((wn << 6) + (ni << 4) + lrow) * 72 +
                                       (kk << 5) + (quad << 3));
          acc[0][ni] = __builtin_amdgcn_mfma_f32_16x16x32_bf16(af0, bf, acc[0][ni], 0, 0, 0);
          acc[1][ni] = __builtin_amdgcn_mfma_f32_16x16x32_bf16(af1, bf, acc[1][ni], 0, 0, 0);
        }
      }
    }
  }

  float* dst = part + ((size_t)blockIdx.y << 21);
#pragma unroll
  for (int mi = 0; mi < 2; ++mi)
#pragma unroll
    for (int ni = 0; ni < 4; ++ni)
#pragma unroll
      for (int r = 0; r < 4; ++r) {
        int m = m0 + (wm << 5) + (mi << 4) + (quad << 2) + r;
        int n = (wn << 6) + (ni << 4) + lrow;
        dst[(size_t)m * 128 + n] = acc[mi][ni][r];
      }
}

// ---------------------------------------------------------------------------
// Reduce: sum 2 split-K partials + bias (float4 loads), transpose to out.
// ---------------------------------------------------------------------------
__global__ __launch_bounds__(256) void paiconv_reduce(
    const void* __restrict__ xprobe, const float* __restrict__ part,
    const void* __restrict__ bias, void* __restrict__ out)
{
  const bool bfm = detect_bf16(xprobe);
  __shared__ float buf[128 * 65];
  const int m0 = blockIdx.x << 6;
  const int b = m0 >> 11, n0 = m0 & 2047;
  const int t = threadIdx.x;

#pragma unroll
  for (int i = 0; i < 8; ++i) {
    int idx = (i * 256 + t) << 2;
    int mt = idx >> 7, c = idx & 127;
    size_t o = (size_t)(m0 + mt) * 128 + c;
    float4 v0 = *(const float4*)(part + o);
    float4 v1 = *(const float4*)(part + (1u << 21) + o);
    buf[(c + 0) * 65 + mt] = v0.x + v1.x + ldin(bias, c + 0, bfm);
    buf[(c + 1) * 65 + mt] = v0.y + v1.y + ldin(bias, c + 1, bfm);
    buf[(c + 2) * 65 + mt] = v0.z + v1.z + ldin(bias, c + 2, bfm);
    buf[(c + 3) * 65 + mt] = v0.w + v1.w + ldin(bias, c + 3, bfm);
  }
  __syncthreads();
#pragma unroll
  for (int i = 0; i < 8; ++i) {
    int idx = (i * 256 + t) << 2;
    int c = idx >> 6, nl = idx & 63;
    float v0 = buf[c * 65 + nl], v1 = buf[c * 65 + nl + 1];
    float v2 = buf[c * 65 + nl + 2], v3 = buf[c * 65 + nl + 3];
    size_t o = (size_t)b * 262144 + (size_t)c * 2048 + n0 + nl;
    if (bfm) *(uint2*)((ushort_t*)out + o) = make_uint2(pk(v0, v1), pk(v2, v3));
    else     *(float4*)((float*)out + o) = make_float4(v0, v1, v2, v3);
  }
}

extern "C" void kernel_launch(void* const* d_in, const int* in_sizes, int n_in,
                              void* d_out, int out_size, void* d_ws, size_t ws_size,
                              hipStream_t stream) {
  const void* x     = d_in[0];
  const void* feat  = d_in[1];
  const int*  nbr   = (const int*)d_in[2];
  const void* Brff  = d_in[3];
  const void* kern  = d_in[4];
  const void* mlpw  = d_in[5];
  const void* mlpb  = d_in[6];
  const void* convw = d_in[7];
  const void* convb = d_in[8];

  char* ws = (char*)d_ws;
  ushort_t* A   = (ushort_t*)ws;                          // 128 MiB
  ushort_t* Wcv = (ushort_t*)(ws + (size_t)134217728);    // 1 MiB
  float*    prt = (float*)(ws + (size_t)135266304);       // 16 MiB
  ushort_t* Ft  = (ushort_t*)(ws + (size_t)152043520);    // 2 MiB

  paiconv_prep<<<512, 256, 0, stream>>>(x, feat, Ft, convw, Wcv);
  paiconv_phase1<<<8192, 256, 0, stream>>>(x, Ft, nbr, Brff, kern, mlpw, mlpb, A);
  paiconv_gemm<<<dim3(256, 2, 1), 256, 0, stream>>>(A, Wcv, prt);
  paiconv_reduce<<<256, 256, 0, stream>>>(x, prt, convb, d_out);
}

// Round 15
// 166.282 us; speedup vs baseline: 1.0812x; 1.0096x over previous
//
#include <hip/hip_runtime.h>
#include <hip/hip_bf16.h>

typedef unsigned short ushort_t;
typedef __attribute__((ext_vector_type(8))) short short8;
typedef __attribute__((ext_vector_type(4))) float floatx4;

#define TWO_PI 6.28318530717958647692f

__device__ __forceinline__ float bf2f(ushort_t u) {
  union { unsigned u; float f; } v; v.u = ((unsigned)u) << 16; return v.f;
}
__device__ __forceinline__ unsigned pk(float a, float b) {
  union { __hip_bfloat162 h2; unsigned u; } v;
  v.h2 = __float22bfloat162_rn(make_float2(a, b));
  return v.u;
}
__device__ __forceinline__ float ldin(const void* p, int idx, bool bf) {
  return bf ? bf2f(((const ushort_t*)p)[idx]) : ((const float*)p)[idx];
}
__device__ __forceinline__ bool detect_bf16(const void* xv) {
  const ushort_t* us = (const ushort_t*)xv;
  unsigned u = us[threadIdx.x & 63];
  int e = (u >> 7) & 0xFF;
  bool good = (e >= 110) && (e <= 133);
  unsigned long long m = __ballot(good);
  return __builtin_popcountll(m) >= 52;
}
__device__ __forceinline__ uint4 pack8f(const float* p) {
  float4 a = *(const float4*)p, b = *(const float4*)(p + 4);
  uint4 r;
  r.x = pk(a.x, a.y); r.y = pk(a.z, a.w);
  r.z = pk(b.x, b.y); r.w = pk(b.z, b.w);
  return r;
}

// ---------------------------------------------------------------------------
// Prep (fused): blocks 0..255 = featT, blocks 256..511 = wconv (shuffle baked).
// ---------------------------------------------------------------------------
__global__ __launch_bounds__(256) void paiconv_prep(
    const void* __restrict__ xprobe, const void* __restrict__ feat,
    ushort_t* __restrict__ Ft, const void* __restrict__ W,
    ushort_t* __restrict__ Wc)
{
  const bool bfm = detect_bf16(xprobe);
  const int t = threadIdx.x;
  __shared__ ushort_t tile[64 * 72];

  if (blockIdx.x >= 256) {
    int i = ((blockIdx.x - 256) * 256 + t) << 3;
    int n = i >> 12, rem = i & 4095;
    int c = rem >> 5, j = rem & 31;
    int src = (n << 12) + (((c & 31) * 4 + (c >> 5)) << 5) + j;
    if (bfm) *(uint4*)(Wc + i) = *(const uint4*)((const ushort_t*)W + src);
    else     *(uint4*)(Wc + i) = pack8f((const float*)W + src);
    return;
  }

  const int bb = blockIdx.x >> 5;
  const int n0 = (blockIdx.x & 31) << 6;
  {
    const int c = t & 63, ng = t >> 6;
    size_t base = (((size_t)(bb * 64 + c)) << 11) + n0 + (ng << 4);
    ushort_t v[16];
    if (bfm) {
      const ushort_t* fp_ = (const ushort_t*)feat + base;
      uint4 a = *(const uint4*)fp_, b2 = *(const uint4*)(fp_ + 8);
      unsigned uu[8] = {a.x, a.y, a.z, a.w, b2.x, b2.y, b2.z, b2.w};
#pragma unroll
      for (int e = 0; e < 8; ++e) {
        v[2 * e] = (ushort_t)(uu[e] & 0xffff);
        v[2 * e + 1] = (ushort_t)(uu[e] >> 16);
      }
    } else {
      const float* fp_ = (const float*)feat + base;
#pragma unroll
      for (int k = 0; k < 16; k += 2) {
        unsigned u = pk(fp_[k], fp_[k + 1]);
        v[k] = (ushort_t)(u & 0xffff);
        v[k + 1] = (ushort_t)(u >> 16);
      }
    }
#pragma unroll
    for (int k = 0; k < 16; ++k) tile[(ng * 16 + k) * 72 + c] = v[k];
  }
  __syncthreads();
  {
    const int nn = t >> 2, qtr = t & 3;
    uint4 w0 = *(const uint4*)(tile + nn * 72 + qtr * 16);
    uint4 w1 = *(const uint4*)(tile + nn * 72 + qtr * 16 + 8);
    ushort_t* dst = Ft + (((size_t)(bb * 2048 + n0 + nn)) << 6) + (qtr << 4);
    *(uint4*)dst = w0;
    *(uint4*)(dst + 8) = w1;
  }
}

// ---------------------------------------------------------------------------
// Phase 1: 2 points/block, point-sequential sF, kern/mlpb hoisted to
// registers -> LDS 27136 B alloc -> 6 blocks/CU.
// ---------------------------------------------------------------------------
#define SFPT 5184
__global__ __launch_bounds__(256) void paiconv_phase1(
    const void* __restrict__ x,       // [8,3,2048]
    const ushort_t* __restrict__ Ft,  // [16384][64] bf16
    const int*  __restrict__ nbr,     // [8,2048,32]
    const void* __restrict__ Brff,    // [7,32]
    const void* __restrict__ kern,    // [3,32]
    const void* __restrict__ mlpw,    // [64,64]
    const void* __restrict__ mlpb,    // [64]
    ushort_t*   __restrict__ Ag)      // [16384,4096] bf16
{
  const bool bfm = detect_bf16(x);
  const int t = threadIdx.x;
  const int p0 = blockIdx.x << 1;
  const int b  = p0 >> 11;
  const int w = t >> 6, lane = t & 63, lrow = lane & 15, quad = lane >> 4;

  __shared__ ushort_t sRt[64 * 72];     // 9.2 KB
  __shared__ ushort_t sF[SFPT];         // 10.4 KB (one point at a time)
  __shared__ ushort_t sP[2 * 32 * 40];  // 5.1 KB
  __shared__ float sRel[2][32][3];
  __shared__ float sDis[2][32];
  __shared__ float sRep[2][3];
  __shared__ float sBr[224];

  // gather prefetch: 16 channels (2 uint4)/thread
  const int gpt = t >> 7, gj = (t >> 2) & 31, gch = t & 3;
  const int gidx = nbr[((p0 + gpt) << 5) + gj];
  const ushort_t* gfr = Ft + (((size_t)(b * 2048 + gidx)) << 6) + (gch << 4);
  uint4 g0 = ((const uint4*)gfr)[0];
  uint4 g1 = ((const uint4*)gfr)[1];

  // per-thread constants hoisted to registers (were sKn / sMb in LDS)
  const int pj = t & 31;
  const float kn0 = ldin(kern, pj, bfm);
  const float kn1 = ldin(kern, 32 + pj, bfm);
  const float kn2 = ldin(kern, 64 + pj, bfm);
  const int mc = (w << 4) + lrow;
  const float bv = ldin(mlpb, mc, bfm);

  short8 mb0, mb1;
  if (bfm) {
    const ushort_t* mp = (const ushort_t*)mlpw + mc * 64;
    mb0 = *(const short8*)(mp + (quad << 3));
    mb1 = *(const short8*)(mp + 32 + (quad << 3));
  } else {
    const float* mp = (const float*)mlpw + mc * 64;
    uint4 u0 = pack8f(mp + (quad << 3));
    uint4 u1 = pack8f(mp + 32 + (quad << 3));
    mb0 = *(short8*)&u0;
    mb1 = *(short8*)&u1;
  }

  if (t < 224) sBr[t] = ldin(Brff, t, bfm);
  if (t < 64) {
    int pt = t >> 5, i = t & 31;
    int p = p0 + pt;
    int idx  = nbr[(p << 5) + i];
    int idx0 = nbr[(p << 5)];
    int xo = b * 6144;
    float rx = ldin(x, xo + idx0, bfm);
    float ry = ldin(x, xo + 2048 + idx0, bfm);
    float rz = ldin(x, xo + 4096 + idx0, bfm);
    float cx = ldin(x, xo + idx, bfm);
    float cy = ldin(x, xo + 2048 + idx, bfm);
    float cz = ldin(x, xo + 4096 + idx, bfm);
    float dx = cx - rx, dy = cy - ry, dz = cz - rz;
    sRel[pt][i][0] = dx; sRel[pt][i][1] = dy; sRel[pt][i][2] = dz;
    sDis[pt][i] = sqrtf(dx * dx + dy * dy + dz * dz);
    if (i == 0) { sRep[pt][0] = rx; sRep[pt][1] = ry; sRep[pt][2] = rz; }
  }
  __syncthreads();   // b1

  // ---- I1: R^T build (all 256) + perm build (t<128) ----
  {
    int jn = t >> 2, mh = (t & 3) << 3;
    int pt = jn >> 5, j = jn & 31;
    float pos[7];
    pos[0] = TWO_PI * sRep[pt][0]; pos[1] = TWO_PI * sRep[pt][1];
    pos[2] = TWO_PI * sRep[pt][2];
    pos[3] = TWO_PI * sRel[pt][j][0]; pos[4] = TWO_PI * sRel[pt][j][1];
    pos[5] = TWO_PI * sRel[pt][j][2];
    pos[6] = TWO_PI * sDis[pt][j];
    unsigned sw[4], cw[4];
#pragma unroll
    for (int mm = 0; mm < 8; mm += 2) {
      float a0 = 0.f, a1 = 0.f;
#pragma unroll
      for (int d = 0; d < 7; ++d) {
        a0 += pos[d] * sBr[d * 32 + mh + mm];
        a1 += pos[d] * sBr[d * 32 + mh + mm + 1];
      }
      sw[mm >> 1] = pk(__sinf(a0), __sinf(a1));
      cw[mm >> 1] = pk(__cosf(a0), __cosf(a1));
    }
    ushort_t* rb = sRt + jn * 72;
    *(uint4*)(rb + mh)      = make_uint4(sw[0], sw[1], sw[2], sw[3]);
    *(uint4*)(rb + 32 + mh) = make_uint4(cw[0], cw[1], cw[2], cw[3]);
  }
  if (t < 128) {
    int pt = t >> 6, h = (t >> 5) & 1;
    float col[16];
    float s1 = 0.f;
#pragma unroll
    for (int il = 0; il < 16; ++il) {
      int i = h * 16 + il;
      float v = sRel[pt][i][0] * kn0 + sRel[pt][i][1] * kn1 + sRel[pt][i][2] * kn2;
      if (i == 0 && pj == 0) v += 1.0f;
      v = fmaxf(v, 0.f);
      col[il] = v; s1 += v;
    }
    s1 += __shfl_xor(s1, 32, 64);
    float inv1 = 1.0f / (s1 + 1e-6f);
    float s2 = 0.f;
#pragma unroll
    for (int il = 0; il < 16; ++il) { float v = col[il] * inv1; v = v * v; col[il] = v; s2 += v; }
    s2 += __shfl_xor(s2, 32, 64);
    float inv2 = 1.0f / (s2 + 1e-6f);
    unsigned pw[8];
#pragma unroll
    for (int il = 0; il < 16; il += 2) {
      float v0 = col[il] * inv2;     v0 = (v0 > 0.1f) ? v0 : 0.f;
      float v1 = col[il + 1] * inv2; v1 = (v1 > 0.1f) ? v1 : 0.f;
      pw[il >> 1] = pk(v0, v1);
    }
    ushort_t* dst = sP + pt * 1280 + pj * 40 + h * 16;
    *(uint4*)dst       = make_uint4(pw[0], pw[1], pw[2], pw[3]);
    *(uint4*)(dst + 8) = make_uint4(pw[4], pw[5], pw[6], pw[7]);
  }
  __syncthreads();   // b2

  const int rbase = (64 + mc) * 40 + ((4 + w) << 3);

#pragma unroll
  for (int pt = 0; pt < 2; ++pt) {
    // ---- fill sF for point pt ----
    {
#pragma unroll
      for (int half = 0; half < 2; ++half) {
        int mt = pt * 2 + half;
        const ushort_t* rp = sRt + (mt * 16 + lrow) * 72 + (quad << 3);
        short8 a0 = *(const short8*)rp;
        short8 a1 = *(const short8*)(rp + 32);
        floatx4 acc = {0.f, 0.f, 0.f, 0.f};
        acc = __builtin_amdgcn_mfma_f32_16x16x32_bf16(a0, mb0, acc, 0, 0, 0);
        acc = __builtin_amdgcn_mfma_f32_16x16x32_bf16(a1, mb1, acc, 0, 0, 0);
        int j0 = (half << 4) + (quad << 2);
        *(uint2*)(sF + rbase + j0) =
            make_uint2(pk(acc[0] + bv, acc[1] + bv), pk(acc[2] + bv, acc[3] + bv));
      }
      if (gpt == pt) {
        ushort_t* fp_ = sF + gch * 648 + gj;
        unsigned uu[8] = {g0.x, g0.y, g0.z, g0.w, g1.x, g1.y, g1.z, g1.w};
#pragma unroll
        for (int u = 0; u < 8; ++u) {
          fp_[(2 * u) * 40]     = (ushort_t)(uu[u] & 0xffff);
          fp_[(2 * u + 1) * 40] = (ushort_t)(uu[u] >> 16);
        }
      }
    }
    __syncthreads();   // b3 / b5

    // ---- F@P via MFMA -> global A for point pt ----
    {
      const ushort_t* Pp = sP + pt * 1280;
      short8 a0 = *(const short8*)(Pp + lrow * 40 + (quad << 3));
      short8 a1 = *(const short8*)(Pp + (16 + lrow) * 40 + (quad << 3));
      size_t prow = ((size_t)(p0 + pt)) << 12;
#pragma unroll
      for (int nt = 0; nt < 2; ++nt) {
        int blk = w * 2 + nt;
        int cidx = (blk << 4) + lrow;
        short8 bfg = *(const short8*)(sF + cidx * 40 + (blk << 3) + (quad << 3));
        floatx4 z = {0.f, 0.f, 0.f, 0.f};
        floatx4 c0 = __builtin_amdgcn_mfma_f32_16x16x32_bf16(a0, bfg, z, 0, 0, 0);
        floatx4 c1 = __builtin_amdgcn_mfma_f32_16x16x32_bf16(a1, bfg, z, 0, 0, 0);
        ushort_t* ad = Ag + prow + cidx * 32 + (quad << 2);
        *(uint2*)ad        = make_uint2(pk(c0[0], c0[1]), pk(c0[2], c0[3]));
        *(uint2*)(ad + 16) = make_uint2(pk(c1[0], c1[1]), pk(c1[2], c1[3]));
      }
    }
    if (pt == 0) __syncthreads();   // b4
  }
}

// ---------------------------------------------------------------------------
// Phase 2: bf16 MFMA GEMM, BM=64 BN=128 BK=64, split-K=2, grid (256,2).
// Dbuf LDS, one barrier per half-iter, manual depth-2 prefetch. (r12 — best)
// ---------------------------------------------------------------------------
__global__ __launch_bounds__(256) void paiconv_gemm(
    const ushort_t* __restrict__ A,
    const ushort_t* __restrict__ Wc,
    float* __restrict__ part)
{
  __shared__ ushort_t lA[2][64 * 72];
  __shared__ ushort_t lB[2][128 * 72];
  const int m0 = blockIdx.x << 6;
  const int K0 = blockIdx.y << 11;
  const int t = threadIdx.x;
  const int w = t >> 6, lane = t & 63;
  const int wm = w & 1, wn = w >> 1, lrow = lane & 15, quad = lane >> 4;

  const int ar = t >> 2, ac = (t & 3) << 4;
  const int wr = t >> 1, wc = (t & 1) << 5;
  const ushort_t* Ap = A + (size_t)(m0 + ar) * 4096 + K0 + ac;
  const ushort_t* Wp = Wc + (size_t)wr * 4096 + K0 + wc;

  uint4 ea0 = *(const uint4*)Ap,        ea1 = *(const uint4*)(Ap + 8);
  uint4 eb0 = *(const uint4*)Wp,        eb1 = *(const uint4*)(Wp + 8);
  uint4 eb2 = *(const uint4*)(Wp + 16), eb3 = *(const uint4*)(Wp + 24);
  uint4 oa0 = *(const uint4*)(Ap + 64),      oa1 = *(const uint4*)(Ap + 72);
  uint4 ob0 = *(const uint4*)(Wp + 64),      ob1 = *(const uint4*)(Wp + 72);
  uint4 ob2 = *(const uint4*)(Wp + 80),      ob3 = *(const uint4*)(Wp + 88);

  floatx4 acc[2][4];
#pragma unroll
  for (int i = 0; i < 2; ++i)
#pragma unroll
    for (int j = 0; j < 4; ++j) acc[i][j] = (floatx4){0.f, 0.f, 0.f, 0.f};

  for (int kb = 0; kb < 32; kb += 2) {
    {
      ushort_t* la = lA[0];
      ushort_t* lb = lB[0];
      *(uint4*)(la + ar * 72 + ac)      = ea0;
      *(uint4*)(la + ar * 72 + ac + 8)  = ea1;
      *(uint4*)(lb + wr * 72 + wc)      = eb0;
      *(uint4*)(lb + wr * 72 + wc + 8)  = eb1;
      *(uint4*)(lb + wr * 72 + wc + 16) = eb2;
      *(uint4*)(lb + wr * 72 + wc + 24) = eb3;
      __syncthreads();
      if (kb + 2 < 32) {
        int off = (kb + 2) << 6;
        ea0 = *(const uint4*)(Ap + off);      ea1 = *(const uint4*)(Ap + off + 8);
        eb0 = *(const uint4*)(Wp + off);      eb1 = *(const uint4*)(Wp + off + 8);
        eb2 = *(const uint4*)(Wp + off + 16); eb3 = *(const uint4*)(Wp + off + 24);
      }
#pragma unroll
      for (int kk = 0; kk < 2; ++kk) {
        short8 af0 = *(const short8*)(la + ((wm << 5) + lrow) * 72 + (kk << 5) + (quad << 3));
        short8 af1 = *(const short8*)(la + ((wm << 5) + 16 + lrow) * 72 + (kk << 5) + (quad << 3));
#pragma unroll
        for (int ni = 0; ni < 4; ++ni) {
          short8 bf = *(const short8*)(lb + ((wn << 6) + (ni << 4) + lrow) * 72 +
                                       (kk << 5) + (quad << 3));
          acc[0][ni] = __builtin_amdgcn_mfma_f32_16x16x32_bf16(af0, bf, acc[0][ni], 0, 0, 0);
          acc[1][ni] = __builtin_amdgcn_mfma_f32_16x16x32_bf16(af1, bf, acc[1][ni], 0, 0, 0);
        }
      }
    }
    {
      ushort_t* la = lA[1];
      ushort_t* lb = lB[1];
      *(uint4*)(la + ar * 72 + ac)      = oa0;
      *(uint4*)(la + ar * 72 + ac + 8)  = oa1;
      *(uint4*)(lb + wr * 72 + wc)      = ob0;
      *(uint4*)(lb + wr * 72 + wc + 8)  = ob1;
      *(uint4*)(lb + wr * 72 + wc + 16) = ob2;
      *(uint4*)(lb + wr * 72 + wc + 24) = ob3;
      __syncthreads();
      if (kb + 3 < 32) {
        int off = (kb + 3) << 6;
        oa0 = *(const uint4*)(Ap + off);      oa1 = *(const uint4*)(Ap + off + 8);
        ob0 = *(const uint4*)(Wp + off);      ob1 = *(const uint4*)(Wp + off + 8);
        ob2 = *(const uint4*)(Wp + off + 16); ob3 = *(const uint4*)(Wp + off + 24);
      }
#pragma unroll
      for (int kk = 0; kk < 2; ++kk) {
        short8 af0 = *(const short8*)(la + ((wm << 5) + lrow) * 72 + (kk << 5) + (quad << 3));
        short8 af1 = *(const short8*)(la + ((wm << 5) + 16 + lrow) * 72 + (kk << 5) + (quad << 3));
#pragma unroll
        for (int ni = 0; ni < 4; ++ni) {
          short8 bf = *(const short8*)(lb + ((wn << 6) + (ni << 4) + lrow) * 72 +
                                       (kk << 5) + (quad << 3));
          acc[0][ni] = __builtin_amdgcn_mfma_f32_16x16x32_bf16(af0, bf, acc[0][ni], 0, 0, 0);
          acc[1][ni] = __builtin_amdgcn_mfma_f32_16x16x32_bf16(af1, bf, acc[1][ni], 0, 0, 0);
        }
      }
    }
  }

  float* dst = part + ((size_t)blockIdx.y << 21);
#pragma unroll
  for (int mi = 0; mi < 2; ++mi)
#pragma unroll
    for (int ni = 0; ni < 4; ++ni)
#pragma unroll
      for (int r = 0; r < 4; ++r) {
        int m = m0 + (wm << 5) + (mi << 4) + (quad << 2) + r;
        int n = (wn << 6) + (ni << 4) + lrow;
        dst[(size_t)m * 128 + n] = acc[mi][ni][r];
      }
}

// ---------------------------------------------------------------------------
// Reduce: sum 2 split-K partials + bias (float4 loads), transpose to out.
// ---------------------------------------------------------------------------
__global__ __launch_bounds__(256) void paiconv_reduce(
    const void* __restrict__ xprobe, const float* __restrict__ part,
    const void* __restrict__ bias, void* __restrict__ out)
{
  const bool bfm = detect_bf16(xprobe);
  __shared__ float buf[128 * 65];
  const int m0 = blockIdx.x << 6;
  const int b = m0 >> 11, n0 = m0 & 2047;
  const int t = threadIdx.x;

#pragma unroll
  for (int i = 0; i < 8; ++i) {
    int idx = (i * 256 + t) << 2;
    int mt = idx >> 7, c = idx & 127;
    size_t o = (size_t)(m0 + mt) * 128 + c;
    float4 v0 = *(const float4*)(part + o);
    float4 v1 = *(const float4*)(part + (1u << 21) + o);
    buf[(c + 0) * 65 + mt] = v0.x + v1.x + ldin(bias, c + 0, bfm);
    buf[(c + 1) * 65 + mt] = v0.y + v1.y + ldin(bias, c + 1, bfm);
    buf[(c + 2) * 65 + mt] = v0.z + v1.z + ldin(bias, c + 2, bfm);
    buf[(c + 3) * 65 + mt] = v0.w + v1.w + ldin(bias, c + 3, bfm);
  }
  __syncthreads();
#pragma unroll
  for (int i = 0; i < 8; ++i) {
    int idx = (i * 256 + t) << 2;
    int c = idx >> 6, nl = idx & 63;
    float v0 = buf[c * 65 + nl], v1 = buf[c * 65 + nl + 1];
    float v2 = buf[c * 65 + nl + 2], v3 = buf[c * 65 + nl + 3];
    size_t o = (size_t)b * 262144 + (size_t)c * 2048 + n0 + nl;
    if (bfm) *(uint2*)((ushort_t*)out + o) = make_uint2(pk(v0, v1), pk(v2, v3));
    else     *(float4*)((float*)out + o) = make_float4(v0, v1, v2, v3);
  }
}

extern "C" void kernel_launch(void* const* d_in, const int* in_sizes, int n_in,
                              void* d_out, int out_size, void* d_ws, size_t ws_size,
                              hipStream_t stream) {
  const void* x     = d_in[0];
  const void* feat  = d_in[1];
  const int*  nbr   = (const int*)d_in[2];
  const void* Brff  = d_in[3];
  const void* kern  = d_in[4];
  const void* mlpw  = d_in[5];
  const void* mlpb  = d_in[6];
  const void* convw = d_in[7];
  const void* convb = d_in[8];

  char* ws = (char*)d_ws;
  ushort_t* A   = (ushort_t*)ws;                          // 128 MiB
  ushort_t* Wcv = (ushort_t*)(ws + (size_t)134217728);    // 1 MiB
  float*    prt = (float*)(ws + (size_t)135266304);       // 16 MiB
  ushort_t* Ft  = (ushort_t*)(ws + (size_t)152043520);    // 2 MiB

  paiconv_prep<<<512, 256, 0, stream>>>(x, feat, Ft, convw, Wcv);
  paiconv_phase1<<<8192, 256, 0, stream>>>(x, Ft, nbr, Brff, kern, mlpw, mlpb, A);
  paiconv_gemm<<<dim3(256, 2, 1), 256, 0, stream>>>(A, Wcv, prt);
  paiconv_reduce<<<256, 256, 0, stream>>>(x, prt, convb, d_out);
}